// Round 5
// baseline (57747.931 us; speedup 1.0000x reference)
//
#include <hip/hip_runtime.h>

typedef __attribute__((ext_vector_type(8))) short bf8v;   // 8 x bf16
typedef __attribute__((ext_vector_type(4))) float fx4;    // MFMA accumulator
typedef unsigned short u16;
typedef unsigned int u32;

__device__ __forceinline__ float b2f(u16 h) {
    u32 u = ((u32)h) << 16; float f; __builtin_memcpy(&f, &u, 4); return f;
}
__device__ __forceinline__ u16 f2b(float f) {
    u32 u; __builtin_memcpy(&u, &f, 4);
    return (u16)((u + 0x7fffu + ((u >> 16) & 1u)) >> 16);
}

template<bool F32>
__device__ __forceinline__ float ld1(const void* p, long off) {
    if constexpr (F32) return ((const float*)p)[off];
    else return b2f(((const u16*)p)[off]);
}
template<bool F32>
__device__ __forceinline__ bf8v ld8(const void* p, long off) {
    if constexpr (!F32) {
        return *(const bf8v*)((const u16*)p + off);
    } else {
        const float* f = (const float*)p + off;
        bf8v r;
#pragma unroll
        for (int j = 0; j < 8; ++j) r[j] = (short)f2b(f[j]);
        return r;
    }
}

__device__ __forceinline__ float gru_out(float sr, float sz, float sn, float xn,
                                         float bxr, float bxz, float bxn,
                                         float bhr, float bhz, float bhn, float hp) {
    float r = 1.f / (1.f + __expf(-(sr + bxr + bhr)));
    float z = 1.f / (1.f + __expf(-(sz + bxz + bhz)));
    float pn = xn + bxn + r * (sn + bhn);
    pn = fminf(fmaxf(pn, -15.f), 15.f);
    float e = __expf(2.f * pn);
    float n = (e - 1.f) / (e + 1.f);
    return n + z * (hp - n);
}

// ---------------------------------------------------------------- zero helpers
__global__ __launch_bounds__(256) void zero_a(uint4* __restrict__ p) {   // 32 blocks: 131072 B
    p[(long)blockIdx.x * 256 + threadIdx.x] = make_uint4(0u, 0u, 0u, 0u);
}
__global__ __launch_bounds__(256) void zero_misc(uint4* __restrict__ p) { // 1 block: 4096 B
    p[threadIdx.x] = make_uint4(0u, 0u, 0u, 0u);
}

// ---------------------------------------------------------------- flags[0]: 1 = inputs fp32
__global__ __launch_bounds__(256) void detect_dtype(const u32* __restrict__ x,
                                                    u32* __restrict__ flags) {
    __shared__ int red[256];
    int t = threadIdx.x;
    int cnt = 0;
    for (int i = t; i < 4096; i += 256) {
        u32 ex = (x[i] >> 7) & 0xff;
        cnt += (ex >= 100 && ex <= 135) ? 1 : 0;
    }
    red[t] = cnt; __syncthreads();
    for (int s = 128; s > 0; s >>= 1) { if (t < s) red[t] += red[t + s]; __syncthreads(); }
    if (t == 0) flags[0] = (red[0] < 2048) ? 1u : 0u;
}

// ---------------------------------------------------------------- flags[1]: layout-A ok, flags[2]: layout-B ok
__global__ __launch_bounds__(64) void selftest_mfma(u32* __restrict__ flags) {
    __shared__ float Af[16 * 32], Bf[32 * 16];
    __shared__ int okA, okB;
    int t = threadIdx.x;
    if (t == 0) { okA = 1; okB = 1; }
    for (int i = t; i < 512; i += 64) {
        int m = i >> 5, k = i & 31;
        Af[i] = (float)(((m * 7 + k * 13) % 17) - 8);
        int kk = i >> 4, n = i & 15;
        Bf[i] = (float)(((kk * 5 + n * 3) % 19) - 9);
    }
    __syncthreads();
    int l15 = t & 15, lk = t >> 4;
    bf8v a, b;
#pragma unroll
    for (int j = 0; j < 8; ++j) {
        a[j] = (short)f2b(Af[l15 * 32 + lk * 8 + j]);
        b[j] = (short)f2b(Bf[(lk * 8 + j) * 16 + l15]);
    }
    fx4 acc = {0.f, 0.f, 0.f, 0.f};
    acc = __builtin_amdgcn_mfma_f32_16x16x32_bf16(a, b, acc, 0, 0, 0);
    int gA = 1, gB = 1;
    for (int reg = 0; reg < 4; ++reg) {
        int rA = lk * 4 + reg, cA = l15;
        int rB = l15, cB = lk * 4 + reg;
        float refA = 0.f, refB = 0.f;
        for (int k = 0; k < 32; ++k) {
            refA += Af[rA * 32 + k] * Bf[k * 16 + cA];
            refB += Af[rB * 32 + k] * Bf[k * 16 + cB];
        }
        if (fabsf(acc[reg] - refA) > 0.5f) gA = 0;
        if (fabsf(acc[reg] - refB) > 0.5f) gB = 0;
    }
    if (!gA) atomicAnd(&okA, 0);
    if (!gB) atomicAnd(&okB, 0);
    __syncthreads();
    if (t == 0) { flags[1] = (u32)okA; flags[2] = (okA ? 0u : (u32)okB); }
}

// ---------------------------------------------------------------- device-scope grid barrier (256 blocks, 1 wave each)
__device__ __forceinline__ void gbar(u32* cnt, u32* gen) {
    __syncthreads();
    u32 g = __hip_atomic_load(gen, __ATOMIC_RELAXED, __HIP_MEMORY_SCOPE_AGENT);
    if (threadIdx.x == 0) {
        u32 v = __hip_atomic_fetch_add(cnt, 1u, __ATOMIC_ACQ_REL, __HIP_MEMORY_SCOPE_AGENT);
        if (v == 255u) {
            __hip_atomic_store(cnt, 0u, __ATOMIC_RELAXED, __HIP_MEMORY_SCOPE_AGENT);
            __hip_atomic_fetch_add(gen, 1u, __ATOMIC_RELEASE, __HIP_MEMORY_SCOPE_AGENT);
        }
    }
    while (__hip_atomic_load(gen, __ATOMIC_ACQUIRE, __HIP_MEMORY_SCOPE_AGENT) == g) {
        __builtin_amdgcn_s_sleep(1);
    }
    __syncthreads();
}

// ================================================================ persistent two-layer GRU
// 256 blocks x 64 threads. Block = (layer = blk>>7, utile16 = (blk&127)>>1, bhalf32 = blk&1).
// Time-synchronous: iteration s runs layer0 t=s and layer1 t=s-1; one grid barrier per iteration.
// LDS: Wh r,z gate slices (32 rows x 1032 padded) staged once; Wh-n + Wx stream from L2.
template<bool WF32, bool MAPA>
__device__ __forceinline__ void persist_impl(short* Wlds, const void* x,
    const void* Wx0, const void* Wh0, const void* bx0, const void* bh0,
    const void* Wx1, const void* Wh1, const void* bx1, const void* bh1,
    const u16* zbuf, u16* h0a, u16* h0b, u16* h1a, u16* h1b,
    u32* cnt, u32* gen) {

    const int blk = blockIdx.x;
    const int layer = blk >> 7;
    const int sub = blk & 127;
    const int u0 = (sub >> 1) * 16;
    const int b0 = (sub & 1) * 32;
    const int l = threadIdx.x, l15 = l & 15, lk = l >> 4;

    const void* Wh = layer ? Wh1 : Wh0;
    const void* Wx = layer ? Wx1 : Wx0;
    const void* bx = layer ? bx1 : bx0;
    const void* bh = layer ? bh1 : bh0;

    // stage r,z Wh slices: rows {u0+0..15, 1024+u0+0..15} -> LDS [32][1032]
    for (int c = l; c < 4096; c += 64) {
        int r = c >> 7;                  // 0..31
        int kc = (c & 127) * 8;
        int g = r >> 4, ur = r & 15;
        *(bf8v*)&Wlds[r * 1032 + kc] = ld8<WF32>(Wh, (long)(g * 1024 + u0 + ur) * 1024 + kc);
    }
    __syncthreads();

    // hoist biases (constant across steps)
    float Bxr[4], Bxz[4], Bxn[4], Bhr[4], Bhz[4], Bhn[4];
#pragma unroll
    for (int reg = 0; reg < 4; ++reg) {
        int u = MAPA ? (u0 + l15) : (u0 + lk * 4 + reg);
        Bxr[reg] = ld1<WF32>(bx, u);        Bhr[reg] = ld1<WF32>(bh, u);
        Bxz[reg] = ld1<WF32>(bx, 1024 + u); Bhz[reg] = ld1<WF32>(bh, 1024 + u);
        Bxn[reg] = ld1<WF32>(bx, 2048 + u); Bhn[reg] = ld1<WF32>(bh, 2048 + u);
    }

    u16* h0buf[2] = { h0a, h0b };
    u16* h1buf[2] = { h1a, h1b };

    for (int s = 0; s <= 512; ++s) {
        const int t = layer ? (s - 1) : s;
        const bool active = layer ? (s >= 1) : (s < 512);
        if (active) {
            const u16* hprev = (t == 0) ? zbuf : (layer ? h1buf[(t - 1) & 1] : h0buf[(t - 1) & 1]);
            u16* hout = layer ? h1buf[t & 1] : h0buf[t & 1];
            const u16* xb = layer ? h0buf[t & 1] : nullptr;   // layer1 input = h0[t] (written last iter)

            fx4 aR[2] = {}, aZ[2] = {}, aN[2] = {}, aXN[2] = {};
            for (int kk = 0; kk < 1024; kk += 32) {
                const int ko = kk + lk * 8;
                bf8v ah[2], axv[2];
#pragma unroll
                for (int m = 0; m < 2; ++m) {
                    int row = b0 + m * 16 + l15;
                    ah[m] = *(const bf8v*)&hprev[(long)row * 1024 + ko];
                    if (layer) axv[m] = *(const bf8v*)&xb[(long)row * 1024 + ko];
                    else       axv[m] = ld8<WF32>(x, (long)row * (512 * 1024) + (long)t * 1024 + ko);
                }
                bf8v hR = *(const bf8v*)&Wlds[l15 * 1032 + ko];
                bf8v hZ = *(const bf8v*)&Wlds[(16 + l15) * 1032 + ko];
                bf8v hN = ld8<WF32>(Wh, (long)(2048 + u0 + l15) * 1024 + ko);
                bf8v xR = ld8<WF32>(Wx, (long)(u0 + l15) * 1024 + ko);
                bf8v xZ = ld8<WF32>(Wx, (long)(1024 + u0 + l15) * 1024 + ko);
                bf8v xN = ld8<WF32>(Wx, (long)(2048 + u0 + l15) * 1024 + ko);
#pragma unroll
                for (int m = 0; m < 2; ++m) {
                    aR[m]  = __builtin_amdgcn_mfma_f32_16x16x32_bf16(ah[m],  hR, aR[m],  0, 0, 0);
                    aZ[m]  = __builtin_amdgcn_mfma_f32_16x16x32_bf16(ah[m],  hZ, aZ[m],  0, 0, 0);
                    aN[m]  = __builtin_amdgcn_mfma_f32_16x16x32_bf16(ah[m],  hN, aN[m],  0, 0, 0);
                    aR[m]  = __builtin_amdgcn_mfma_f32_16x16x32_bf16(axv[m], xR, aR[m],  0, 0, 0);
                    aZ[m]  = __builtin_amdgcn_mfma_f32_16x16x32_bf16(axv[m], xZ, aZ[m],  0, 0, 0);
                    aXN[m] = __builtin_amdgcn_mfma_f32_16x16x32_bf16(axv[m], xN, aXN[m], 0, 0, 0);
                }
            }
#pragma unroll
            for (int m = 0; m < 2; ++m)
#pragma unroll
                for (int reg = 0; reg < 4; ++reg) {
                    int bi, u;
                    if (MAPA) { bi = b0 + m * 16 + lk * 4 + reg; u = u0 + l15; }
                    else      { bi = b0 + m * 16 + l15;          u = u0 + lk * 4 + reg; }
                    float hp = b2f(hprev[(long)bi * 1024 + u]);
                    float hv = gru_out(aR[m][reg], aZ[m][reg], aN[m][reg], aXN[m][reg],
                                       Bxr[reg], Bxz[reg], Bxn[reg],
                                       Bhr[reg], Bhz[reg], Bhn[reg], hp);
                    hout[(long)bi * 1024 + u] = f2b(hv);
                }
        }
        gbar(cnt, gen);
    }
}

__global__ __launch_bounds__(64) void gru_persist(const void* x,
    const void* Wx0, const void* Wh0, const void* bx0, const void* bh0,
    const void* Wx1, const void* Wh1, const void* bx1, const void* bh1,
    const u16* zbuf, u16* h0a, u16* h0b, u16* h1a, u16* h1b,
    const u32* flags, u32* cnt, u32* gen) {
    __shared__ short Wlds[32 * 1032];     // 66048 B -> 2 blocks/CU schedulable
    bool wf32 = flags[0] != 0;
    bool mapA = flags[1] != 0;
    if (!wf32 && mapA)
        persist_impl<false, true>(Wlds, x, Wx0, Wh0, bx0, bh0, Wx1, Wh1, bx1, bh1,
                                  zbuf, h0a, h0b, h1a, h1b, cnt, gen);
    else if (!wf32)
        persist_impl<false, false>(Wlds, x, Wx0, Wh0, bx0, bh0, Wx1, Wh1, bx1, bh1,
                                   zbuf, h0a, h0b, h1a, h1b, cnt, gen);
    else if (mapA)
        persist_impl<true, true>(Wlds, x, Wx0, Wh0, bx0, bh0, Wx1, Wh1, bx1, bh1,
                                 zbuf, h0a, h0b, h1a, h1b, cnt, gen);
    else
        persist_impl<true, false>(Wlds, x, Wx0, Wh0, bx0, bh0, Wx1, Wh1, bx1, bh1,
                                  zbuf, h0a, h0b, h1a, h1b, cnt, gen);
}

// ---------------------------------------------------------------- final FC: fp32 output
__global__ __launch_bounds__(256) void fc_out(const u16* __restrict__ h,
                                              const void* __restrict__ fcW,
                                              const void* __restrict__ fcb,
                                              const u32* __restrict__ flags,
                                              float* __restrict__ out) {
    bool f32 = flags[0] != 0;
    __shared__ float red[256];
    int t = threadIdx.x, b = t >> 2, q = t & 3;
    float s = 0.f;
    for (int u = q * 256; u < q * 256 + 256; ++u) {
        float w = f32 ? ((const float*)fcW)[u] : b2f(((const u16*)fcW)[u]);
        s += b2f(h[(long)b * 1024 + u]) * w;
    }
    red[t] = s; __syncthreads();
    if (q == 0) {
        float fb = f32 ? ((const float*)fcb)[0] : b2f(((const u16*)fcb)[0]);
        out[b] = red[t] + red[t + 1] + red[t + 2] + red[t + 3] + fb;
    }
}

// ================================================================ host
extern "C" void kernel_launch(void* const* d_in, const int* in_sizes, int n_in,
                              void* d_out, int out_size, void* d_ws, size_t ws_size,
                              hipStream_t stream) {
    (void)in_sizes; (void)n_in; (void)out_size; (void)ws_size;
    char* ws = (char*)d_ws;
    u16* zbuf = (u16*)ws;                  // 131072 B zeros (initial h)
    u16* h0a  = (u16*)(ws + 131072);
    u16* h0b  = (u16*)(ws + 262144);
    u16* h1a  = (u16*)(ws + 393216);
    u16* h1b  = (u16*)(ws + 524288);
    u32* misc = (u32*)(ws + 655360);       // flags[0..7], cnt, gen
    u32* flags = misc;
    u32* cnt = misc + 8;
    u32* gen = misc + 9;

    zero_a<<<32, 256, 0, stream>>>((uint4*)d_ws);
    zero_misc<<<1, 256, 0, stream>>>((uint4*)(ws + 655360));
    detect_dtype<<<1, 256, 0, stream>>>((const u32*)d_in[0], flags);
    selftest_mfma<<<1, 64, 0, stream>>>(flags);

    gru_persist<<<256, 64, 0, stream>>>(d_in[0],
        d_in[1], d_in[3], d_in[2], d_in[4],      // Wx0, Wh0, bx0, bh0
        d_in[5], d_in[7], d_in[6], d_in[8],      // Wx1, Wh1, bx1, bh1
        zbuf, h0a, h0b, h1a, h1b, flags, cnt, gen);

    fc_out<<<1, 256, 0, stream>>>(h1b, d_in[9], d_in[10], flags, (float*)d_out);
}

// Round 6
// 31852.390 us; speedup vs baseline: 1.8130x; 1.8130x over previous
//
#include <hip/hip_runtime.h>

typedef __attribute__((ext_vector_type(8))) short bf8v;   // 8 x bf16
typedef __attribute__((ext_vector_type(4))) float fx4;    // MFMA accumulator
typedef unsigned short u16;
typedef unsigned int u32;

__device__ __forceinline__ float b2f(u16 h) {
    u32 u = ((u32)h) << 16; float f; __builtin_memcpy(&f, &u, 4); return f;
}
__device__ __forceinline__ u16 f2b(float f) {
    u32 u; __builtin_memcpy(&u, &f, 4);
    return (u16)((u + 0x7fffu + ((u >> 16) & 1u)) >> 16);
}

template<bool F32>
__device__ __forceinline__ float ld1(const void* p, long off) {
    if constexpr (F32) return ((const float*)p)[off];
    else return b2f(((const u16*)p)[off]);
}
template<bool F32>
__device__ __forceinline__ bf8v ld8(const void* p, long off) {
    if constexpr (!F32) {
        return *(const bf8v*)((const u16*)p + off);
    } else {
        const float* f = (const float*)p + off;
        bf8v r;
#pragma unroll
        for (int j = 0; j < 8; ++j) r[j] = (short)f2b(f[j]);
        return r;
    }
}

__device__ __forceinline__ float gru_out(float sr, float sz, float sn, float xn,
                                         float bxr, float bxz, float bxn,
                                         float bhr, float bhz, float bhn, float hp) {
    float r = 1.f / (1.f + __expf(-(sr + bxr + bhr)));
    float z = 1.f / (1.f + __expf(-(sz + bxz + bhz)));
    float pn = xn + bxn + r * (sn + bhn);
    pn = fminf(fmaxf(pn, -15.f), 15.f);
    float e = __expf(2.f * pn);
    float n = (e - 1.f) / (e + 1.f);
    return n + z * (hp - n);
}

// ---------------------------------------------------------------- zero helpers
__global__ __launch_bounds__(256) void zero_a(uint4* __restrict__ p) {    // 32 blocks: 131072 B (zbuf)
    p[(long)blockIdx.x * 256 + threadIdx.x] = make_uint4(0u, 0u, 0u, 0u);
}
__global__ __launch_bounds__(256) void zero_misc(uint4* __restrict__ p) { // 2 blocks: 8192 B
    p[(long)blockIdx.x * 256 + threadIdx.x] = make_uint4(0u, 0u, 0u, 0u);
}

// ---------------------------------------------------------------- flags[0]: 1 = inputs fp32
__global__ __launch_bounds__(256) void detect_dtype(const u32* __restrict__ x,
                                                    u32* __restrict__ flags) {
    __shared__ int red[256];
    int t = threadIdx.x;
    int cnt = 0;
    for (int i = t; i < 4096; i += 256) {
        u32 ex = (x[i] >> 7) & 0xff;
        cnt += (ex >= 100 && ex <= 135) ? 1 : 0;
    }
    red[t] = cnt; __syncthreads();
    for (int s = 128; s > 0; s >>= 1) { if (t < s) red[t] += red[t + s]; __syncthreads(); }
    if (t == 0) flags[0] = (red[0] < 2048) ? 1u : 0u;
}

// ---------------------------------------------------------------- flags[1]: layout-A ok, flags[2]: layout-B ok
__global__ __launch_bounds__(64) void selftest_mfma(u32* __restrict__ flags) {
    __shared__ float Af[16 * 32], Bf[32 * 16];
    __shared__ int okA, okB;
    int t = threadIdx.x;
    if (t == 0) { okA = 1; okB = 1; }
    for (int i = t; i < 512; i += 64) {
        int m = i >> 5, k = i & 31;
        Af[i] = (float)(((m * 7 + k * 13) % 17) - 8);
        int kk = i >> 4, n = i & 15;
        Bf[i] = (float)(((kk * 5 + n * 3) % 19) - 9);
    }
    __syncthreads();
    int l15 = t & 15, lk = t >> 4;
    bf8v a, b;
#pragma unroll
    for (int j = 0; j < 8; ++j) {
        a[j] = (short)f2b(Af[l15 * 32 + lk * 8 + j]);
        b[j] = (short)f2b(Bf[(lk * 8 + j) * 16 + l15]);
    }
    fx4 acc = {0.f, 0.f, 0.f, 0.f};
    acc = __builtin_amdgcn_mfma_f32_16x16x32_bf16(a, b, acc, 0, 0, 0);
    int gA = 1, gB = 1;
    for (int reg = 0; reg < 4; ++reg) {
        int rA = lk * 4 + reg, cA = l15;
        int rB = l15, cB = lk * 4 + reg;
        float refA = 0.f, refB = 0.f;
        for (int k = 0; k < 32; ++k) {
            refA += Af[rA * 32 + k] * Bf[k * 16 + cA];
            refB += Af[rB * 32 + k] * Bf[k * 16 + cB];
        }
        if (fabsf(acc[reg] - refA) > 0.5f) gA = 0;
        if (fabsf(acc[reg] - refB) > 0.5f) gB = 0;
    }
    if (!gA) atomicAnd(&okA, 0);
    if (!gB) atomicAnd(&okB, 0);
    __syncthreads();
    if (t == 0) { flags[1] = (u32)okA; flags[2] = (okA ? 0u : (u32)okB); }
}

// ---------------------------------------------------------------- contention-free grid barrier
// 64 blocks. Each block release-stores its own flag (separate cachelines, no RMW).
// Block 0 polls all 64 flags in parallel (1 per lane), then release-stores gen.
__device__ __forceinline__ void gbar(u32* bflags, u32* gen, u32 target) {
    __syncthreads();
    if (threadIdx.x == 0)
        __hip_atomic_store(&bflags[(u32)blockIdx.x * 16u], target,
                           __ATOMIC_RELEASE, __HIP_MEMORY_SCOPE_AGENT);
    if (blockIdx.x == 0) {
        if (threadIdx.x < 64) {
            while (__hip_atomic_load(&bflags[(u32)threadIdx.x * 16u],
                                     __ATOMIC_ACQUIRE, __HIP_MEMORY_SCOPE_AGENT) < target)
                __builtin_amdgcn_s_sleep(1);
        }
        __syncthreads();
        if (threadIdx.x == 0)
            __hip_atomic_store(gen, target, __ATOMIC_RELEASE, __HIP_MEMORY_SCOPE_AGENT);
    }
    while (__hip_atomic_load(gen, __ATOMIC_ACQUIRE, __HIP_MEMORY_SCOPE_AGENT) < target)
        __builtin_amdgcn_s_sleep(2);
    __syncthreads();
}

// ================================================================ persistent two-layer GRU
// 64 blocks x 256 threads (4 waves). blk = (layer = blk>>5, utile32 = blk&31).
// Wave w: batch half (w&1)*32, unit half (w>>1)*16 -> each wave: 32 batch x 16 units x 3 gates.
// LDS: Wh r,z slices (64 rows x 1032 padded bf16) staged once = 132 KB.
// Streams (L2-resident via blk%8 XCD grouping: 8 blocks/XCD x 256 KB = 2 MB): Wh-n, Wx r/z/n.
// Time-skew: iteration s = layer0 step s, layer1 step s-1; one barrier per iteration.
template<bool WF32, bool MAPA>
__device__ __forceinline__ void persist_impl(short* Wlds, const void* x,
    const void* Wx0, const void* Wh0, const void* bx0, const void* bh0,
    const void* Wx1, const void* Wh1, const void* bx1, const void* bh1,
    const u16* zbuf, u16* h0a, u16* h0b, u16* h1a, u16* h1b,
    u32* bflags, u32* gen) {

    const int blk = blockIdx.x;
    const int layer = blk >> 5;
    const int u0 = (blk & 31) * 32;
    const int tid = threadIdx.x;
    const int w = tid >> 6, l = tid & 63, l15 = l & 15, lk = l >> 4;
    const int nhalf = w >> 1, bb = (w & 1) * 32;
    const int un = u0 + nhalf * 16;

    const void* Wh = layer ? Wh1 : Wh0;
    const void* Wx = layer ? Wx1 : Wx0;
    const void* bx = layer ? bx1 : bx0;
    const void* bh = layer ? bh1 : bh0;

    // stage Wh r,z rows u0..u0+31 -> LDS rows [gate*32 + ur] x 1032
    for (int c = tid; c < 8192; c += 256) {
        int r = c >> 7;                    // 0..63
        int kc = (c & 127) * 8;
        int g = r >> 5, ur = r & 31;
        *(bf8v*)&Wlds[r * 1032 + kc] = ld8<WF32>(Wh, (long)(g * 1024 + u0 + ur) * 1024 + kc);
    }
    __syncthreads();

    // hoist biases
    float Bxr[4], Bxz[4], Bxn[4], Bhr[4], Bhz[4], Bhn[4];
#pragma unroll
    for (int reg = 0; reg < 4; ++reg) {
        int u = MAPA ? (un + l15) : (un + lk * 4 + reg);
        Bxr[reg] = ld1<WF32>(bx, u);        Bhr[reg] = ld1<WF32>(bh, u);
        Bxz[reg] = ld1<WF32>(bx, 1024 + u); Bhz[reg] = ld1<WF32>(bh, 1024 + u);
        Bxn[reg] = ld1<WF32>(bx, 2048 + u); Bhn[reg] = ld1<WF32>(bh, 2048 + u);
    }

    u16* h0buf[2] = { h0a, h0b };
    u16* h1buf[2] = { h1a, h1b };
    const long koff = lk * 8;
    const long rWn = (long)(2048 + un + l15) * 1024;   // Wh-n row
    const long rXr = (long)(un + l15) * 1024;          // Wx-r row
    const long rXz = (long)(1024 + un + l15) * 1024;   // Wx-z row
    const long rXn = (long)(2048 + un + l15) * 1024;   // Wx-n row
    const int ldsR = (nhalf * 16 + l15) * 1032;
    const int ldsZ = (32 + nhalf * 16 + l15) * 1032;

    for (int s = 0; s <= 512; ++s) {
        const int t = layer ? (s - 1) : s;
        const bool active = layer ? (s >= 1) : (s < 512);
        if (active) {
            const u16* hprev = (t == 0) ? zbuf : (layer ? h1buf[(t - 1) & 1] : h0buf[(t - 1) & 1]);
            u16* hout = layer ? h1buf[t & 1] : h0buf[t & 1];
            const u16* xb = layer ? h0buf[t & 1] : nullptr;  // layer1 input = h0[t]

            const long hr0 = (long)(bb + l15) * 1024;
            const long hr1 = (long)(bb + 16 + l15) * 1024;
            long xr0, xr1;
            if (layer) { xr0 = hr0; xr1 = hr1; }
            else {
                xr0 = (long)(bb + l15) * (512 * 1024) + (long)t * 1024;
                xr1 = (long)(bb + 16 + l15) * (512 * 1024) + (long)t * 1024;
            }
            const u16* xs16 = layer ? xb : (const u16*)x;   // unified bf16 x source

            fx4 aR[2] = {}, aZ[2] = {}, aN[2] = {}, aXN[2] = {};
            // prime software pipeline (kk = 0)
            bf8v cWn = ld8<WF32>(Wh, rWn + koff);
            bf8v cXr = ld8<WF32>(Wx, rXr + koff);
            bf8v cXz = ld8<WF32>(Wx, rXz + koff);
            bf8v cXn = ld8<WF32>(Wx, rXn + koff);
            bf8v cH0 = *(const bf8v*)&hprev[hr0 + koff];
            bf8v cH1 = *(const bf8v*)&hprev[hr1 + koff];
            bf8v cX0, cX1;
            if constexpr (!WF32) { cX0 = *(const bf8v*)&xs16[xr0 + koff]; cX1 = *(const bf8v*)&xs16[xr1 + koff]; }
            else {
                if (layer) { cX0 = *(const bf8v*)&xb[xr0 + koff]; cX1 = *(const bf8v*)&xb[xr1 + koff]; }
                else       { cX0 = ld8<true>(x, xr0 + koff);      cX1 = ld8<true>(x, xr1 + koff); }
            }

            for (int kk = 0; kk < 1024; kk += 32) {
                const int k2 = (kk + 32 < 1024) ? (kk + 32) : kk;
                const long ko2 = k2 + koff;
                // prefetch next iteration
                bf8v nWn = ld8<WF32>(Wh, rWn + ko2);
                bf8v nXr = ld8<WF32>(Wx, rXr + ko2);
                bf8v nXz = ld8<WF32>(Wx, rXz + ko2);
                bf8v nXn = ld8<WF32>(Wx, rXn + ko2);
                bf8v nH0 = *(const bf8v*)&hprev[hr0 + ko2];
                bf8v nH1 = *(const bf8v*)&hprev[hr1 + ko2];
                bf8v nX0, nX1;
                if constexpr (!WF32) { nX0 = *(const bf8v*)&xs16[xr0 + ko2]; nX1 = *(const bf8v*)&xs16[xr1 + ko2]; }
                else {
                    if (layer) { nX0 = *(const bf8v*)&xb[xr0 + ko2]; nX1 = *(const bf8v*)&xb[xr1 + ko2]; }
                    else       { nX0 = ld8<true>(x, xr0 + ko2);      nX1 = ld8<true>(x, xr1 + ko2); }
                }
                const long ko = kk + koff;
                bf8v hRf = *(const bf8v*)&Wlds[ldsR + ko];
                bf8v hZf = *(const bf8v*)&Wlds[ldsZ + ko];

                aR[0]  = __builtin_amdgcn_mfma_f32_16x16x32_bf16(cH0, hRf, aR[0], 0, 0, 0);
                aR[1]  = __builtin_amdgcn_mfma_f32_16x16x32_bf16(cH1, hRf, aR[1], 0, 0, 0);
                aZ[0]  = __builtin_amdgcn_mfma_f32_16x16x32_bf16(cH0, hZf, aZ[0], 0, 0, 0);
                aZ[1]  = __builtin_amdgcn_mfma_f32_16x16x32_bf16(cH1, hZf, aZ[1], 0, 0, 0);
                aN[0]  = __builtin_amdgcn_mfma_f32_16x16x32_bf16(cH0, cWn, aN[0], 0, 0, 0);
                aN[1]  = __builtin_amdgcn_mfma_f32_16x16x32_bf16(cH1, cWn, aN[1], 0, 0, 0);
                aR[0]  = __builtin_amdgcn_mfma_f32_16x16x32_bf16(cX0, cXr, aR[0], 0, 0, 0);
                aR[1]  = __builtin_amdgcn_mfma_f32_16x16x32_bf16(cX1, cXr, aR[1], 0, 0, 0);
                aZ[0]  = __builtin_amdgcn_mfma_f32_16x16x32_bf16(cX0, cXz, aZ[0], 0, 0, 0);
                aZ[1]  = __builtin_amdgcn_mfma_f32_16x16x32_bf16(cX1, cXz, aZ[1], 0, 0, 0);
                aXN[0] = __builtin_amdgcn_mfma_f32_16x16x32_bf16(cX0, cXn, aXN[0], 0, 0, 0);
                aXN[1] = __builtin_amdgcn_mfma_f32_16x16x32_bf16(cX1, cXn, aXN[1], 0, 0, 0);

                cWn = nWn; cXr = nXr; cXz = nXz; cXn = nXn;
                cH0 = nH0; cH1 = nH1; cX0 = nX0; cX1 = nX1;
            }
#pragma unroll
            for (int m = 0; m < 2; ++m)
#pragma unroll
                for (int reg = 0; reg < 4; ++reg) {
                    int bi, u;
                    if (MAPA) { bi = bb + m * 16 + lk * 4 + reg; u = un + l15; }
                    else      { bi = bb + m * 16 + l15;          u = un + lk * 4 + reg; }
                    float hp = b2f(hprev[(long)bi * 1024 + u]);
                    float hv = gru_out(aR[m][reg], aZ[m][reg], aN[m][reg], aXN[m][reg],
                                       Bxr[reg], Bxz[reg], Bxn[reg],
                                       Bhr[reg], Bhz[reg], Bhn[reg], hp);
                    hout[(long)bi * 1024 + u] = f2b(hv);
                }
        }
        gbar(bflags, gen, (u32)(s + 1));
    }
}

__global__ __launch_bounds__(256) void gru_persist(const void* x,
    const void* Wx0, const void* Wh0, const void* bx0, const void* bh0,
    const void* Wx1, const void* Wh1, const void* bx1, const void* bh1,
    const u16* zbuf, u16* h0a, u16* h0b, u16* h1a, u16* h1b,
    const u32* flags, u32* bflags, u32* gen) {
    __shared__ short Wlds[64 * 1032];     // 132096 B
    bool wf32 = flags[0] != 0;
    bool mapA = flags[1] != 0;
    if (!wf32 && mapA)
        persist_impl<false, true>(Wlds, x, Wx0, Wh0, bx0, bh0, Wx1, Wh1, bx1, bh1,
                                  zbuf, h0a, h0b, h1a, h1b, bflags, gen);
    else if (!wf32)
        persist_impl<false, false>(Wlds, x, Wx0, Wh0, bx0, bh0, Wx1, Wh1, bx1, bh1,
                                   zbuf, h0a, h0b, h1a, h1b, bflags, gen);
    else if (mapA)
        persist_impl<true, true>(Wlds, x, Wx0, Wh0, bx0, bh0, Wx1, Wh1, bx1, bh1,
                                 zbuf, h0a, h0b, h1a, h1b, bflags, gen);
    else
        persist_impl<true, false>(Wlds, x, Wx0, Wh0, bx0, bh0, Wx1, Wh1, bx1, bh1,
                                  zbuf, h0a, h0b, h1a, h1b, bflags, gen);
}

// ---------------------------------------------------------------- final FC: fp32 output
__global__ __launch_bounds__(256) void fc_out(const u16* __restrict__ h,
                                              const void* __restrict__ fcW,
                                              const void* __restrict__ fcb,
                                              const u32* __restrict__ flags,
                                              float* __restrict__ out) {
    bool f32 = flags[0] != 0;
    __shared__ float red[256];
    int t = threadIdx.x, b = t >> 2, q = t & 3;
    float s = 0.f;
    for (int u = q * 256; u < q * 256 + 256; ++u) {
        float w = f32 ? ((const float*)fcW)[u] : b2f(((const u16*)fcW)[u]);
        s += b2f(h[(long)b * 1024 + u]) * w;
    }
    red[t] = s; __syncthreads();
    if (q == 0) {
        float fb = f32 ? ((const float*)fcb)[0] : b2f(((const u16*)fcb)[0]);
        out[b] = red[t] + red[t + 1] + red[t + 2] + red[t + 3] + fb;
    }
}

// ================================================================ host
extern "C" void kernel_launch(void* const* d_in, const int* in_sizes, int n_in,
                              void* d_out, int out_size, void* d_ws, size_t ws_size,
                              hipStream_t stream) {
    (void)in_sizes; (void)n_in; (void)out_size; (void)ws_size;
    char* ws = (char*)d_ws;
    u16* zbuf = (u16*)ws;                  // 131072 B zeros (initial h)
    u16* h0a  = (u16*)(ws + 131072);
    u16* h0b  = (u16*)(ws + 262144);
    u16* h1a  = (u16*)(ws + 393216);
    u16* h1b  = (u16*)(ws + 524288);
    u32* misc = (u32*)(ws + 655360);       // 4096 B: flags + gen
    u32* flags = misc;                     // [0..7]
    u32* gen   = misc + 16;                // own cacheline
    u32* bflags = (u32*)(ws + 659456);     // 4096 B: 64 flags x 64 B stride

    zero_a<<<32, 256, 0, stream>>>((uint4*)d_ws);
    zero_misc<<<2, 256, 0, stream>>>((uint4*)(ws + 655360));
    detect_dtype<<<1, 256, 0, stream>>>((const u32*)d_in[0], flags);
    selftest_mfma<<<1, 64, 0, stream>>>(flags);

    gru_persist<<<64, 256, 0, stream>>>(d_in[0],
        d_in[1], d_in[3], d_in[2], d_in[4],      // Wx0, Wh0, bx0, bh0
        d_in[5], d_in[7], d_in[6], d_in[8],      // Wx1, Wh1, bx1, bh1
        zbuf, h0a, h0b, h1a, h1b, flags, bflags, gen);

    fc_out<<<1, 256, 0, stream>>>(h1b, d_in[9], d_in[10], flags, (float*)d_out);
}